// Round 1
// baseline (278.878 us; speedup 1.0000x reference)
//
#include <hip/hip_runtime.h>

typedef float f32x4 __attribute__((ext_vector_type(4)));
typedef short bf16x8 __attribute__((ext_vector_type(8)));

#define MFMA16(a, b, c) __builtin_amdgcn_mfma_f32_16x16x32_bf16((a), (b), (c), 0, 0, 0)

constexpr int S_ = 2048;
constexpr int D_ = 768;
constexpr int H_ = 12;
constexpr int DH = 64;
constexpr int B_ = 2;
constexpr int M_ = B_ * S_;   // 4096 rows
constexpr int BH = B_ * H_;   // 24 (b,h) pairs

typedef unsigned short u16;
typedef unsigned int u32;

__device__ __forceinline__ u16 f2bf(float f) {
  u32 u = __builtin_bit_cast(u32, f);
  u += 0x7fffu + ((u >> 16) & 1u);
  return (u16)(u >> 16);
}
__device__ __forceinline__ u32 pack2(float a, float b) {
  return (u32)f2bf(a) | ((u32)f2bf(b) << 16);
}

// ---------------- fp32 -> bf16 bulk convert (hidden states) ----------------
__global__ __launch_bounds__(256) void conv_bf16(const float* __restrict__ in,
                                                 u16* __restrict__ out) {
  int i = blockIdx.x * 256 + threadIdx.x;  // one float4 per thread
  float4 v = ((const float4*)in)[i];
  uint2 r;
  r.x = pack2(v.x, v.y);
  r.y = pack2(v.z, v.w);
  ((uint2*)out)[i] = r;
}

// ---------------- W[k][n] fp32 -> Wt[n][k] bf16 (transpose+convert) --------
__global__ __launch_bounds__(256) void conv_wT(const float* __restrict__ w,
                                               u16* __restrict__ wt) {
  __shared__ float t[32][33];
  int k0 = blockIdx.x << 5, n0 = blockIdx.y << 5;
  int x = threadIdx.x & 31, y = threadIdx.x >> 5;  // 32 x 8
#pragma unroll
  for (int j = 0; j < 4; ++j) t[y + 8 * j][x] = w[(size_t)(k0 + y + 8 * j) * D_ + n0 + x];
  __syncthreads();
#pragma unroll
  for (int j = 0; j < 4; ++j) wt[(size_t)(n0 + y + 8 * j) * D_ + k0 + x] = f2bf(t[x][y + 8 * j]);
}

// ---------------- mask canonicalization (bool-bytes or int32 -> int32) -----
__global__ __launch_bounds__(256) void canon_mask(const void* __restrict__ mraw,
                                                  int* __restrict__ mout) {
  __shared__ int isBool;
  int tid = threadIdx.x;
  if (tid == 0) isBool = 0;
  __syncthreads();
  const int* mi = (const int*)mraw;
  int v = mi[tid];  // first 1KB only: safe in both interpretations
  if (v != 0 && v != 1) atomicOr(&isBool, 1);
  __syncthreads();
  const unsigned char* mb = (const unsigned char*)mraw;
  if (isBool) {
    for (int i = tid; i < B_ * S_; i += 256) mout[i] = (int)mb[i];
  } else {
    for (int i = tid; i < B_ * S_; i += 256) mout[i] = mi[i];
  }
}

// ---------------- GEMM: A[4096x768]bf16 @ Wt(n,k)[768x768]bf16 + bias ------
// MODE 0: out bf16 in head-layout [b][h][s][d]   (Q, K, V)
// MODE 2: out fp32 flat [m][n]                   (final output)
template <int MODE>
__global__ __launch_bounds__(256) void gemm64(const u16* __restrict__ A,
                                              const u16* __restrict__ Wt,
                                              const float* __restrict__ bias,
                                              void* __restrict__ outp, float scale) {
  __shared__ __align__(16) u16 lA[64][40];
  __shared__ __align__(16) u16 lB[64][40];
  int tid = threadIdx.x;
  int m0 = blockIdx.x * 64, n0 = blockIdx.y * 64;
  int wid = tid >> 6, lane = tid & 63, g = lane >> 4, c = lane & 15;
  int row = tid >> 2, cc = (tid & 3) * 8;

  f32x4 acc[4] = {};
  for (int k0 = 0; k0 < D_; k0 += 32) {
    uint4 va = *(const uint4*)(A + (size_t)(m0 + row) * D_ + k0 + cc);
    uint4 vb = *(const uint4*)(Wt + (size_t)(n0 + row) * D_ + k0 + cc);
    *(uint4*)&lA[row][cc] = va;
    *(uint4*)&lB[row][cc] = vb;
    __syncthreads();
    bf16x8 af = *(const bf16x8*)&lA[wid * 16 + c][g * 8];
#pragma unroll
    for (int j = 0; j < 4; ++j) {
      bf16x8 bf = *(const bf16x8*)&lB[j * 16 + c][g * 8];
      acc[j] = MFMA16(af, bf, acc[j]);
    }
    __syncthreads();
  }

#pragma unroll
  for (int j = 0; j < 4; ++j) {
    int n = n0 + j * 16 + c;
    float bv = bias[n];
    int h = n >> 6, d = n & 63;
#pragma unroll
    for (int r = 0; r < 4; ++r) {
      int m = m0 + wid * 16 + g * 4 + r;
      float v = (acc[j][r] + bv) * scale;
      if (MODE == 0) {
        int b = m >> 11, s = m & (S_ - 1);
        ((u16*)outp)[((size_t)(b * H_ + h) * S_ + s) * DH + d] = f2bf(v);
      } else {
        ((float*)outp)[(size_t)m * D_ + n] = v;
      }
    }
  }
}

// ---------------- V [bh][s][d] -> Vt [bh][d][s] ----------------------------
__global__ __launch_bounds__(256) void transpose_v(const u16* __restrict__ v,
                                                   u16* __restrict__ vt) {
  __shared__ u16 t[64][72];
  int blk = blockIdx.x;
  int bh = blk >> 5, s0 = (blk & 31) << 6;
  int tid = threadIdx.x;
  int r = tid >> 2, cs = (tid & 3) << 4;
  const u16* src = v + ((size_t)bh * S_ + s0 + r) * DH + cs;
  uint4 x0 = *(const uint4*)(src);
  uint4 x1 = *(const uint4*)(src + 8);
  const u16* p0 = (const u16*)&x0;
  const u16* p1 = (const u16*)&x1;
#pragma unroll
  for (int i = 0; i < 8; ++i) {
    t[cs + i][r] = p0[i];
    t[cs + 8 + i][r] = p1[i];
  }
  __syncthreads();
  u16* dst = vt + ((size_t)bh * DH + r) * S_ + s0 + cs;
  uint4 y0 = *(const uint4*)&t[r][cs];
  uint4 y1 = *(const uint4*)&t[r][cs + 8];
  *(uint4*)(dst) = y0;
  *(uint4*)(dst + 8) = y1;
}

// ---------------- dual-softmax flash attention -----------------------------
// grid (S/16, B*H), block 64 (one wave). Q pre-scaled by 1/8.
__global__ __launch_bounds__(64) void attn(const u16* __restrict__ Q,
                                           const u16* __restrict__ K,
                                           const u16* __restrict__ Vt,
                                           const int* __restrict__ cmask,
                                           u16* __restrict__ ctx) {
  int qt = blockIdx.x, bh = blockIdx.y;
  int b = bh / H_, h = bh % H_;
  int lane = threadIdx.x, g = lane >> 4, c = lane & 15;
  const u16* Qp = Q + ((size_t)bh * S_ + qt * 16) * DH;
  const u16* Kp = K + (size_t)bh * S_ * DH;
  const u16* Vp = Vt + (size_t)bh * DH * S_;
  const int* mp = cmask + b * S_;

  __shared__ __align__(16) u16 pl[2][16][40];

  bf16x8 qf0 = *(const bf16x8*)(Qp + c * DH + g * 8);
  bf16x8 qf1 = *(const bf16x8*)(Qp + c * DH + 32 + g * 8);

  f32x4 accf[4] = {}, accb[4] = {};
  float lf = 0.f, lb = 0.f;

  for (int kb = 0; kb < S_ / 32; ++kb) {
    int kbase = kb * 32;
    const u16* kp = Kp + (size_t)(kbase + c) * DH + g * 8;
    bf16x8 k00 = *(const bf16x8*)(kp);
    bf16x8 k01 = *(const bf16x8*)(kp + 32);
    bf16x8 k10 = *(const bf16x8*)(kp + 16 * DH);
    bf16x8 k11 = *(const bf16x8*)(kp + 16 * DH + 32);

    f32x4 st0 = {}, st1 = {};
    st0 = MFMA16(k00, qf0, st0);
    st0 = MFMA16(k01, qf1, st0);
    st1 = MFMA16(k10, qf0, st1);
    st1 = MFMA16(k11, qf1, st1);

    // exp + classify by key mask. lane holds ST[key][q]: q=c, key=kbase+{4g+r, 16+4g+r}
    float pf[8], pb[8];
#pragma unroll
    for (int r = 0; r < 4; ++r) {
      int key0 = kbase + g * 4 + r;
      int key1 = key0 + 16;
      float e0 = __expf(st0[r]);
      float e1 = __expf(st1[r]);
      bool m0 = mp[key0] != 0;
      bool m1 = mp[key1] != 0;
      float f0 = m0 ? e0 : 0.f, b0 = m0 ? 0.f : e0;
      float f1 = m1 ? e1 : 0.f, b1 = m1 ? 0.f : e1;
      lf += f0 + f1;
      lb += b0 + b1;
      pf[r] = f0; pf[4 + r] = f1;
      pb[r] = b0; pb[4 + r] = b1;
    }

    // P round-trip through LDS to re-fragment for PV (same wave, no barrier)
    uint2 wf0; wf0.x = pack2(pf[0], pf[1]); wf0.y = pack2(pf[2], pf[3]);
    uint2 wf1; wf1.x = pack2(pf[4], pf[5]); wf1.y = pack2(pf[6], pf[7]);
    uint2 wb0; wb0.x = pack2(pb[0], pb[1]); wb0.y = pack2(pb[2], pb[3]);
    uint2 wb1; wb1.x = pack2(pb[4], pb[5]); wb1.y = pack2(pb[6], pb[7]);
    *(uint2*)&pl[0][c][4 * g] = wf0;
    *(uint2*)&pl[0][c][16 + 4 * g] = wf1;
    *(uint2*)&pl[1][c][4 * g] = wb0;
    *(uint2*)&pl[1][c][16 + 4 * g] = wb1;

    bf16x8 paf = *(const bf16x8*)&pl[0][c][g * 8];
    bf16x8 pab = *(const bf16x8*)&pl[1][c][g * 8];

    const u16* vp = Vp + (size_t)c * S_ + kbase + g * 8;
#pragma unroll
    for (int n = 0; n < 4; ++n) {
      bf16x8 vf = *(const bf16x8*)(vp + (size_t)n * 16 * S_);
      accf[n] = MFMA16(paf, vf, accf[n]);
      accb[n] = MFMA16(pab, vf, accb[n]);
    }
  }

  // reduce per-q group sums across the 4 lane-groups (bits 4,5)
  lf += __shfl_xor(lf, 16); lf += __shfl_xor(lf, 32);
  lb += __shfl_xor(lb, 16); lb += __shfl_xor(lb, 32);

  int qbase = qt * 16;
#pragma unroll
  for (int r = 0; r < 4; ++r) {
    int ql = g * 4 + r;  // output D row = q within tile
    float lfr = __shfl(lf, ql);
    float lbr = __shfl(lb, ql);
    bool fg = mp[qbase + ql] != 0;
    float inv_f = (lfr > 0.f) ? 1.f / lfr : 0.f;
    float inv_b = (lbr > 0.f) ? 1.f / lbr : 0.f;
    float inv_all = 1.f / (lfr + lbr);
#pragma unroll
    for (int n = 0; n < 4; ++n) {
      float o;
      if (fg)
        o = accf[n][r] * inv_f + accb[n][r] * inv_b;
      else
        o = (accf[n][r] + accb[n][r]) * inv_all;
      ctx[((size_t)(b * S_ + qbase + ql)) * D_ + h * DH + n * 16 + c] = f2bf(o);
    }
  }
}

// ---------------- launch ---------------------------------------------------
extern "C" void kernel_launch(void* const* d_in, const int* in_sizes, int n_in,
                              void* d_out, int out_size, void* d_ws, size_t ws_size,
                              hipStream_t stream) {
  const float* hs = (const float*)d_in[0];
  const float* Wq = (const float*)d_in[1];
  const float* bq = (const float*)d_in[2];
  const float* Wk = (const float*)d_in[3];
  const float* bk = (const float*)d_in[4];
  const float* Wv = (const float*)d_in[5];
  const float* bv = (const float*)d_in[6];
  const float* Wo = (const float*)d_in[7];
  const float* bo = (const float*)d_in[8];
  const void* mraw = d_in[9];

  char* ws = (char*)d_ws;
  size_t off = 0;
  auto alloc = [&](size_t bytes) {
    void* p = ws + off;
    off += (bytes + 255) & ~(size_t)255;
    return p;
  };
  u16* hsb = (u16*)alloc((size_t)M_ * D_ * 2);
  u16* wqT = (u16*)alloc((size_t)D_ * D_ * 2);
  u16* wkT = (u16*)alloc((size_t)D_ * D_ * 2);
  u16* wvT = (u16*)alloc((size_t)D_ * D_ * 2);
  u16* woT = (u16*)alloc((size_t)D_ * D_ * 2);
  u16* qb = (u16*)alloc((size_t)M_ * D_ * 2);
  u16* kb = (u16*)alloc((size_t)M_ * D_ * 2);
  u16* vb = (u16*)alloc((size_t)M_ * D_ * 2);
  u16* vtb = (u16*)alloc((size_t)M_ * D_ * 2);
  u16* ctx = (u16*)alloc((size_t)M_ * D_ * 2);
  int* cm = (int*)alloc((size_t)B_ * S_ * 4);

  conv_bf16<<<(M_ * D_ / 4 + 255) / 256, 256, 0, stream>>>(hs, hsb);
  dim3 tg(D_ / 32, D_ / 32);
  conv_wT<<<tg, 256, 0, stream>>>(Wq, wqT);
  conv_wT<<<tg, 256, 0, stream>>>(Wk, wkT);
  conv_wT<<<tg, 256, 0, stream>>>(Wv, wvT);
  conv_wT<<<tg, 256, 0, stream>>>(Wo, woT);
  canon_mask<<<1, 256, 0, stream>>>(mraw, cm);

  dim3 gg(M_ / 64, D_ / 64);
  gemm64<0><<<gg, 256, 0, stream>>>(hsb, wqT, bq, qb, 0.125f);  // Q pre-scaled 1/sqrt(Dh)
  gemm64<0><<<gg, 256, 0, stream>>>(hsb, wkT, bk, kb, 1.0f);
  gemm64<0><<<gg, 256, 0, stream>>>(hsb, wvT, bv, vb, 1.0f);

  transpose_v<<<BH * (S_ / 64), 256, 0, stream>>>(vb, vtb);

  attn<<<dim3(S_ / 16, BH), 64, 0, stream>>>(qb, kb, vtb, cm, ctx);

  gemm64<2><<<gg, 256, 0, stream>>>(ctx, woT, bo, d_out, 1.0f);
}

// Round 2
// 169.978 us; speedup vs baseline: 1.6407x; 1.6407x over previous
//
#include <hip/hip_runtime.h>

typedef float f32x4 __attribute__((ext_vector_type(4)));
typedef short bf16x8 __attribute__((ext_vector_type(8)));

#define MFMA16(a, b, c) __builtin_amdgcn_mfma_f32_16x16x32_bf16((a), (b), (c), 0, 0, 0)

constexpr int S_ = 2048;
constexpr int D_ = 768;
constexpr int H_ = 12;
constexpr int DH = 64;
constexpr int B_ = 2;
constexpr int M_ = B_ * S_;   // 4096 rows
constexpr int BH = B_ * H_;   // 24 (b,h) pairs

typedef unsigned short u16;
typedef unsigned int u32;

__device__ __forceinline__ u16 f2bf(float f) {
  u32 u = __builtin_bit_cast(u32, f);
  u += 0x7fffu + ((u >> 16) & 1u);
  return (u16)(u >> 16);
}
__device__ __forceinline__ u32 pack2(float a, float b) {
  return (u32)f2bf(a) | ((u32)f2bf(b) << 16);
}

// async global->LDS, 16B per lane. LDS dest = wave-uniform base + lane*16.
__device__ __forceinline__ void gload16(const void* g, void* l) {
  __builtin_amdgcn_global_load_lds((const __attribute__((address_space(1))) u32*)g,
                                   (__attribute__((address_space(3))) u32*)l, 16, 0, 0);
}

// ---------------- fp32 -> bf16 bulk convert (hidden states) ----------------
__global__ __launch_bounds__(256) void conv_bf16(const float* __restrict__ in,
                                                 u16* __restrict__ out) {
  int i = blockIdx.x * 256 + threadIdx.x;  // one float4 per thread
  float4 v = ((const float4*)in)[i];
  uint2 r;
  r.x = pack2(v.x, v.y);
  r.y = pack2(v.z, v.w);
  ((uint2*)out)[i] = r;
}

// ---------------- W[k][n] fp32 -> Wt[n][k] bf16 (transpose+convert) --------
__global__ __launch_bounds__(256) void conv_wT(const float* __restrict__ w,
                                               u16* __restrict__ wt) {
  __shared__ float t[32][33];
  int k0 = blockIdx.x << 5, n0 = blockIdx.y << 5;
  int x = threadIdx.x & 31, y = threadIdx.x >> 5;  // 32 x 8
#pragma unroll
  for (int j = 0; j < 4; ++j) t[y + 8 * j][x] = w[(size_t)(k0 + y + 8 * j) * D_ + n0 + x];
  __syncthreads();
#pragma unroll
  for (int j = 0; j < 4; ++j) wt[(size_t)(n0 + y + 8 * j) * D_ + k0 + x] = f2bf(t[x][y + 8 * j]);
}

// ---------------- mask canonicalization -> float 1.0/0.0 -------------------
__global__ __launch_bounds__(256) void canon_mask(const void* __restrict__ mraw,
                                                  float* __restrict__ fm) {
  __shared__ int isBool;
  int tid = threadIdx.x;
  if (tid == 0) isBool = 0;
  __syncthreads();
  const int* mi = (const int*)mraw;
  int v = mi[tid];  // first 1KB only: safe in both interpretations
  if (v != 0 && v != 1) atomicOr(&isBool, 1);
  __syncthreads();
  const unsigned char* mb = (const unsigned char*)mraw;
  int i = blockIdx.x * 256 + tid;
  fm[i] = isBool ? (float)mb[i] : (float)mi[i];
}

// ---------------- GEMM: A[4096x768]bf16 @ Wt(n,k)[768x768]bf16 + bias ------
// MODE 0: out bf16 in head-layout [b][h][s][d]   (Q, K, V)
// MODE 2: out fp32 flat [m][n]                   (final output)
template <int MODE>
__global__ __launch_bounds__(256) void gemm64(const u16* __restrict__ A,
                                              const u16* __restrict__ Wt,
                                              const float* __restrict__ bias,
                                              void* __restrict__ outp, float scale) {
  __shared__ __align__(16) u16 lA[64][40];
  __shared__ __align__(16) u16 lB[64][40];
  int tid = threadIdx.x;
  int m0 = blockIdx.x * 64, n0 = blockIdx.y * 64;
  int wid = tid >> 6, lane = tid & 63, g = lane >> 4, c = lane & 15;
  int row = tid >> 2, cc = (tid & 3) * 8;

  f32x4 acc[4] = {};
  for (int k0 = 0; k0 < D_; k0 += 32) {
    uint4 va = *(const uint4*)(A + (size_t)(m0 + row) * D_ + k0 + cc);
    uint4 vb = *(const uint4*)(Wt + (size_t)(n0 + row) * D_ + k0 + cc);
    *(uint4*)&lA[row][cc] = va;
    *(uint4*)&lB[row][cc] = vb;
    __syncthreads();
    bf16x8 af = *(const bf16x8*)&lA[wid * 16 + c][g * 8];
#pragma unroll
    for (int j = 0; j < 4; ++j) {
      bf16x8 bf = *(const bf16x8*)&lB[j * 16 + c][g * 8];
      acc[j] = MFMA16(af, bf, acc[j]);
    }
    __syncthreads();
  }

#pragma unroll
  for (int j = 0; j < 4; ++j) {
    int n = n0 + j * 16 + c;
    float bv = bias[n];
    int h = n >> 6, d = n & 63;
#pragma unroll
    for (int r = 0; r < 4; ++r) {
      int m = m0 + wid * 16 + g * 4 + r;
      float v = (acc[j][r] + bv) * scale;
      if (MODE == 0) {
        int b = m >> 11, s = m & (S_ - 1);
        ((u16*)outp)[((size_t)(b * H_ + h) * S_ + s) * DH + d] = f2bf(v);
      } else {
        ((float*)outp)[(size_t)m * D_ + n] = v;
      }
    }
  }
}

// ---------------- V [bh][s][d] -> Vt [bh][d][s] ----------------------------
__global__ __launch_bounds__(256) void transpose_v(const u16* __restrict__ v,
                                                   u16* __restrict__ vt) {
  __shared__ u16 t[64][72];
  int blk = blockIdx.x;
  int bh = blk >> 5, s0 = (blk & 31) << 6;
  int tid = threadIdx.x;
  int r = tid >> 2, cs = (tid & 3) << 4;
  const u16* src = v + ((size_t)bh * S_ + s0 + r) * DH + cs;
  uint4 x0 = *(const uint4*)(src);
  uint4 x1 = *(const uint4*)(src + 8);
  const u16* p0 = (const u16*)&x0;
  const u16* p1 = (const u16*)&x1;
#pragma unroll
  for (int i = 0; i < 8; ++i) {
    t[cs + i][r] = p0[i];
    t[cs + 8 + i][r] = p1[i];
  }
  __syncthreads();
  u16* dst = vt + ((size_t)bh * DH + r) * S_ + s0 + cs;
  uint4 y0 = *(const uint4*)&t[r][cs];
  uint4 y1 = *(const uint4*)&t[r][cs + 8];
  *(uint4*)(dst) = y0;
  *(uint4*)(dst + 8) = y1;
}

// ---------------- dual-softmax flash attention (staged, 4 waves) -----------
// grid (S/64, B*H), block 256. Wave w owns q rows qt*64 + w*16 .. +16.
// K-tile [64 keys][64 d] and Vt-tile [64 d][64 keys] staged in LDS,
// XOR-swizzled (byte ^= (row&7)<<4), double-buffered via global_load_lds.
__global__ __launch_bounds__(256, 3) void attn(const u16* __restrict__ Q,
                                               const u16* __restrict__ K,
                                               const u16* __restrict__ Vt,
                                               const float* __restrict__ fm,
                                               u16* __restrict__ ctx) {
  constexpr int NT = S_ / 64;
  __shared__ __align__(16) u16 lK[2][64 * 64];
  __shared__ __align__(16) u16 lV[2][64 * 64];
  __shared__ __align__(16) u16 lP[4][2][16][40];

  const int tid = threadIdx.x;
  const int w = tid >> 6, lane = tid & 63;
  const int g = lane >> 4, c = lane & 15;
  const int qt = blockIdx.x, bh = blockIdx.y;
  const int b = bh / H_, h = bh % H_;
  const int qbase = qt * 64;

  const u16* Qp = Q + ((size_t)bh * S_ + qbase + w * 16) * DH;
  const char* Kp = (const char*)(K + (size_t)bh * S_ * DH);
  const char* Vp = (const char*)(Vt + (size_t)bh * DH * S_);
  const float* fmp = fm + b * S_;

  // Q fragments in registers (B-operand): q = c, d-slices kk*32 + g*8
  bf16x8 qf0 = *(const bf16x8*)(Qp + c * DH + g * 8);
  bf16x8 qf1 = *(const bf16x8*)(Qp + c * DH + 32 + g * 8);

  // staging geometry: each wave-instr covers 8 rows x 128B; lane l -> row +l/8,
  // linear colbyte (l&7)*16; source pre-swizzled so swizzled READ is linear.
  const int srow = lane >> 3;
  const int scb = ((lane & 7) * 16) ^ (srow << 4);
  const int r8a = w * 2, r8b = w * 2 + 1;
  const int rowA = r8a * 8 + srow, rowB = r8b * 8 + srow;

  const int sw = (c & 7) << 4;
  const int cswA = (g * 16) ^ sw;        // col-chunk 0 (bytes 0..63)
  const int cswB = (64 + g * 16) ^ sw;   // col-chunk 1 (bytes 64..127)

  f32x4 accf[4] = {}, accb[4] = {};
  float lf = 0.f, lb = 0.f;

  // prologue: stage tile 0 into buf 0
  gload16(Kp + (size_t)rowA * 128 + scb, &lK[0][r8a * 512]);
  gload16(Kp + (size_t)rowB * 128 + scb, &lK[0][r8b * 512]);
  gload16(Vp + (size_t)rowA * 4096 + scb, &lV[0][r8a * 512]);
  gload16(Vp + (size_t)rowB * 4096 + scb, &lV[0][r8b * 512]);
  __syncthreads();

  int buf = 0;
  for (int t = 0; t < NT; ++t) {
    if (t + 1 < NT) {  // issue next-tile loads (in flight during compute)
      const char* kb_ = Kp + (size_t)(t + 1) * 64 * 128;
      const char* vb_ = Vp + (size_t)(t + 1) * 128;
      u16* dK = lK[buf ^ 1];
      u16* dV = lV[buf ^ 1];
      gload16(kb_ + (size_t)rowA * 128 + scb, dK + r8a * 512);
      gload16(kb_ + (size_t)rowB * 128 + scb, dK + r8b * 512);
      gload16(vb_ + (size_t)rowA * 4096 + scb, dV + r8a * 512);
      gload16(vb_ + (size_t)rowB * 4096 + scb, dV + r8b * 512);
    }

    const char* kt = (const char*)lK[buf];
    const char* vtl = (const char*)lV[buf];

#pragma unroll
    for (int kc = 0; kc < 2; ++kc) {
      const int csel = kc ? cswB : cswA;
      // K fragments (A-operand): rows = keys, swizzled read
      bf16x8 k00 = *(const bf16x8*)(kt + (kc * 32 + c) * 128 + cswA);
      bf16x8 k01 = *(const bf16x8*)(kt + (kc * 32 + c) * 128 + cswB);
      bf16x8 k10 = *(const bf16x8*)(kt + (kc * 32 + 16 + c) * 128 + cswA);
      bf16x8 k11 = *(const bf16x8*)(kt + (kc * 32 + 16 + c) * 128 + cswB);
      // V^T fragments (B-operand): rows = d, cols = this 32-key slice
      bf16x8 vf0 = *(const bf16x8*)(vtl + (0 * 16 + c) * 128 + csel);
      bf16x8 vf1 = *(const bf16x8*)(vtl + (1 * 16 + c) * 128 + csel);
      bf16x8 vf2 = *(const bf16x8*)(vtl + (2 * 16 + c) * 128 + csel);
      bf16x8 vf3 = *(const bf16x8*)(vtl + (3 * 16 + c) * 128 + csel);

      f32x4 st0 = {}, st1 = {};
      st0 = MFMA16(k00, qf0, st0);
      st0 = MFMA16(k01, qf1, st0);
      st1 = MFMA16(k10, qf0, st1);
      st1 = MFMA16(k11, qf1, st1);

      const int kb64 = t * 64 + kc * 32;
      float4 f40 = *(const float4*)(fmp + kb64 + g * 4);
      float4 f41 = *(const float4*)(fmp + kb64 + 16 + g * 4);
      const float* fm0 = (const float*)&f40;
      const float* fm1 = (const float*)&f41;

      float pf[8], pb[8];
#pragma unroll
      for (int r = 0; r < 4; ++r) {
        float e0 = __expf(st0[r]);
        float e1 = __expf(st1[r]);
        float f0 = e0 * fm0[r], b0 = e0 - f0;
        float f1 = e1 * fm1[r], b1 = e1 - f1;
        lf += f0 + f1;
        lb += b0 + b1;
        pf[r] = f0; pf[4 + r] = f1;
        pb[r] = b0; pb[4 + r] = b1;
      }

      uint2 wf0, wf1, wb0, wb1;
      wf0.x = pack2(pf[0], pf[1]); wf0.y = pack2(pf[2], pf[3]);
      wf1.x = pack2(pf[4], pf[5]); wf1.y = pack2(pf[6], pf[7]);
      wb0.x = pack2(pb[0], pb[1]); wb0.y = pack2(pb[2], pb[3]);
      wb1.x = pack2(pb[4], pb[5]); wb1.y = pack2(pb[6], pb[7]);
      *(uint2*)&lP[w][0][c][g * 4] = wf0;
      *(uint2*)&lP[w][0][c][16 + g * 4] = wf1;
      *(uint2*)&lP[w][1][c][g * 4] = wb0;
      *(uint2*)&lP[w][1][c][16 + g * 4] = wb1;

      bf16x8 paf = *(const bf16x8*)&lP[w][0][c][g * 8];
      bf16x8 pab = *(const bf16x8*)&lP[w][1][c][g * 8];

      accf[0] = MFMA16(paf, vf0, accf[0]);
      accb[0] = MFMA16(pab, vf0, accb[0]);
      accf[1] = MFMA16(paf, vf1, accf[1]);
      accb[1] = MFMA16(pab, vf1, accb[1]);
      accf[2] = MFMA16(paf, vf2, accf[2]);
      accb[2] = MFMA16(pab, vf2, accb[2]);
      accf[3] = MFMA16(paf, vf3, accf[3]);
      accb[3] = MFMA16(pab, vf3, accb[3]);
    }
    __syncthreads();  // drains next-tile loads; all waves done with buf
    buf ^= 1;
  }

  // per-q group sums: reduce across lane-groups (bits 4,5)
  lf += __shfl_xor(lf, 16); lf += __shfl_xor(lf, 32);
  lb += __shfl_xor(lb, 16); lb += __shfl_xor(lb, 32);

  const int qw = qbase + w * 16;
#pragma unroll
  for (int r = 0; r < 4; ++r) {
    int ql = g * 4 + r;
    float lfr = __shfl(lf, ql);
    float lbr = __shfl(lb, ql);
    bool fg = fmp[qw + ql] > 0.5f;
    float inv_f = (lfr > 0.f) ? 1.f / lfr : 0.f;
    float inv_b = (lbr > 0.f) ? 1.f / lbr : 0.f;
    float inv_all = 1.f / (lfr + lbr);
#pragma unroll
    for (int n = 0; n < 4; ++n) {
      float o = fg ? (accf[n][r] * inv_f + accb[n][r] * inv_b)
                   : ((accf[n][r] + accb[n][r]) * inv_all);
      ctx[((size_t)(b * S_ + qw + ql)) * D_ + h * DH + n * 16 + c] = f2bf(o);
    }
  }
}

// ---------------- launch ---------------------------------------------------
extern "C" void kernel_launch(void* const* d_in, const int* in_sizes, int n_in,
                              void* d_out, int out_size, void* d_ws, size_t ws_size,
                              hipStream_t stream) {
  const float* hs = (const float*)d_in[0];
  const float* Wq = (const float*)d_in[1];
  const float* bq = (const float*)d_in[2];
  const float* Wk = (const float*)d_in[3];
  const float* bk = (const float*)d_in[4];
  const float* Wv = (const float*)d_in[5];
  const float* bv = (const float*)d_in[6];
  const float* Wo = (const float*)d_in[7];
  const float* bo = (const float*)d_in[8];
  const void* mraw = d_in[9];

  char* ws = (char*)d_ws;
  size_t off = 0;
  auto alloc = [&](size_t bytes) {
    void* p = ws + off;
    off += (bytes + 255) & ~(size_t)255;
    return p;
  };
  u16* hsb = (u16*)alloc((size_t)M_ * D_ * 2);
  u16* wqT = (u16*)alloc((size_t)D_ * D_ * 2);
  u16* wkT = (u16*)alloc((size_t)D_ * D_ * 2);
  u16* wvT = (u16*)alloc((size_t)D_ * D_ * 2);
  u16* woT = (u16*)alloc((size_t)D_ * D_ * 2);
  u16* qb = (u16*)alloc((size_t)M_ * D_ * 2);
  u16* kb = (u16*)alloc((size_t)M_ * D_ * 2);
  u16* vb = (u16*)alloc((size_t)M_ * D_ * 2);
  u16* vtb = (u16*)alloc((size_t)M_ * D_ * 2);
  u16* ctx = (u16*)alloc((size_t)M_ * D_ * 2);
  float* fmf = (float*)alloc((size_t)B_ * S_ * 4);

  conv_bf16<<<(M_ * D_ / 4 + 255) / 256, 256, 0, stream>>>(hs, hsb);
  dim3 tg(D_ / 32, D_ / 32);
  conv_wT<<<tg, 256, 0, stream>>>(Wq, wqT);
  conv_wT<<<tg, 256, 0, stream>>>(Wk, wkT);
  conv_wT<<<tg, 256, 0, stream>>>(Wv, wvT);
  conv_wT<<<tg, 256, 0, stream>>>(Wo, woT);
  canon_mask<<<B_ * S_ / 256, 256, 0, stream>>>(mraw, fmf);

  dim3 gg(M_ / 64, D_ / 64);
  gemm64<0><<<gg, 256, 0, stream>>>(hsb, wqT, bq, qb, 0.125f);  // Q pre-scaled 1/sqrt(Dh)
  gemm64<0><<<gg, 256, 0, stream>>>(hsb, wkT, bk, kb, 1.0f);
  gemm64<0><<<gg, 256, 0, stream>>>(hsb, wvT, bv, vb, 1.0f);

  transpose_v<<<BH * (S_ / 64), 256, 0, stream>>>(vb, vtb);

  attn<<<dim3(S_ / 64, BH), 256, 0, stream>>>(qb, kb, vtb, fmf, ctx);

  gemm64<2><<<gg, 256, 0, stream>>>(ctx, woT, bo, d_out, 1.0f);
}

// Round 3
// 114.957 us; speedup vs baseline: 2.4259x; 1.4786x over previous
//
#include <hip/hip_runtime.h>

typedef float f32x4 __attribute__((ext_vector_type(4)));
typedef short bf16x8 __attribute__((ext_vector_type(8)));

#define MFMA16(a, b, c) __builtin_amdgcn_mfma_f32_16x16x32_bf16((a), (b), (c), 0, 0, 0)

constexpr int S_ = 2048;
constexpr int D_ = 768;
constexpr int H_ = 12;
constexpr int DH = 64;
constexpr int B_ = 2;
constexpr int M_ = B_ * S_;   // 4096 rows
constexpr int BH = B_ * H_;   // 24 (b,h) pairs

typedef unsigned short u16;
typedef unsigned int u32;

__device__ __forceinline__ u16 f2bf(float f) {  // RNE
  u32 u = __builtin_bit_cast(u32, f);
  u += 0x7fffu + ((u >> 16) & 1u);
  return (u16)(u >> 16);
}
__device__ __forceinline__ u32 pack2(float a, float b) {  // RNE pair
  return (u32)f2bf(a) | ((u32)f2bf(b) << 16);
}
// round-half-up bf16 pack via v_perm: low16=bf16(lo), high16=bf16(hi). 3 VALU ops.
__device__ __forceinline__ u32 pack2r(float lo, float hi) {
  u32 a = __builtin_bit_cast(u32, lo) + 0x8000u;
  u32 b = __builtin_bit_cast(u32, hi) + 0x8000u;
  return __builtin_amdgcn_perm(b, a, 0x07060302u);  // bytes: [b.b3 b.b2 a.b3 a.b2]
}

// async global->LDS, 16B per lane. LDS dest = wave-uniform base + lane*16.
__device__ __forceinline__ void gload16(const void* g, void* l) {
  __builtin_amdgcn_global_load_lds((const __attribute__((address_space(1))) u32*)g,
                                   (__attribute__((address_space(3))) u32*)l, 16, 0, 0);
}

// ---------------- fp32 -> bf16 bulk convert (hidden states) ----------------
__global__ __launch_bounds__(256) void conv_bf16(const float* __restrict__ in,
                                                 u16* __restrict__ out) {
  int i = blockIdx.x * 256 + threadIdx.x;  // one float4 per thread
  float4 v = ((const float4*)in)[i];
  uint2 r;
  r.x = pack2(v.x, v.y);
  r.y = pack2(v.z, v.w);
  ((uint2*)out)[i] = r;
}

// ---------------- 4x W[k][n] fp32 -> Wt[n][k] bf16 (one launch) ------------
struct WPtrs {
  const float* s0; const float* s1; const float* s2; const float* s3;
  u16* d0; u16* d1; u16* d2; u16* d3;
};
__global__ __launch_bounds__(256) void conv_wT4(WPtrs p) {
  __shared__ float t[32][33];
  int z = blockIdx.z;
  const float* w = z == 0 ? p.s0 : z == 1 ? p.s1 : z == 2 ? p.s2 : p.s3;
  u16* wt = z == 0 ? p.d0 : z == 1 ? p.d1 : z == 2 ? p.d2 : p.d3;
  int k0 = blockIdx.x << 5, n0 = blockIdx.y << 5;
  int x = threadIdx.x & 31, y = threadIdx.x >> 5;  // 32 x 8
#pragma unroll
  for (int j = 0; j < 4; ++j) t[y + 8 * j][x] = w[(size_t)(k0 + y + 8 * j) * D_ + n0 + x];
  __syncthreads();
#pragma unroll
  for (int j = 0; j < 4; ++j) wt[(size_t)(n0 + y + 8 * j) * D_ + k0 + x] = f2bf(t[x][y + 8 * j]);
}

// ------ mask canonicalization -> float 1.0/0.0 and packed bf16-AND words ---
// mw[pair] = (m[2p]?0xFFFF:0) | (m[2p+1]?0xFFFF0000:0)
__global__ __launch_bounds__(256) void canon_mask(const void* __restrict__ mraw,
                                                  float* __restrict__ fm,
                                                  u32* __restrict__ mw) {
  __shared__ int isBool;
  int tid = threadIdx.x;
  if (tid == 0) isBool = 0;
  __syncthreads();
  const int* mi = (const int*)mraw;
  int v = mi[tid];  // first 1KB only: safe in both interpretations
  if (v != 0 && v != 1) atomicOr(&isBool, 1);
  __syncthreads();
  const unsigned char* mb = (const unsigned char*)mraw;
  int p = blockIdx.x * 256 + tid;  // pair index, 0 .. B*S/2-1
  int m0, m1;
  if (isBool) { m0 = mb[2 * p]; m1 = mb[2 * p + 1]; }
  else        { m0 = mi[2 * p]; m1 = mi[2 * p + 1]; }
  fm[2 * p] = (float)m0;
  fm[2 * p + 1] = (float)m1;
  mw[p] = (m0 ? 0xFFFFu : 0u) | (m1 ? 0xFFFF0000u : 0u);
}

// ---------------- GEMM: A[4096x768]bf16 @ Wt(n,k)[768x768]bf16 + bias ------
// 64x64 tile, BK=64, double-buffered global_load_lds, XOR-swizzled LDS.
// MODE 0: out bf16 head-layout [b][h][s][d]        (Q, K)
// MODE 1: out bf16 VtPerm [b][h][d][sigma(s)]      (V, pre-permuted cols)
// MODE 2: out fp32 flat [m][n]                     (final output)
template <int MODE>
__global__ __launch_bounds__(256) void gemm64(const u16* __restrict__ A,
                                              const u16* __restrict__ Wt,
                                              const float* __restrict__ bias,
                                              void* __restrict__ outp, float scale) {
  __shared__ __align__(16) u16 lA[2][64 * 64];
  __shared__ __align__(16) u16 lB[2][64 * 64];
  int tid = threadIdx.x;
  int w = tid >> 6, lane = tid & 63, g = lane >> 4, c = lane & 15;
  int m0 = blockIdx.x * 64, n0 = blockIdx.y * 64;
  int srow = lane >> 3;                       // 0..7
  int scb = ((lane & 7) * 16) ^ (srow << 4);  // pre-swizzled source col within 128B
  int sw = (c & 7) << 4;
  const char* Ab = (const char*)A + (size_t)m0 * (D_ * 2);
  const char* Bb = (const char*)Wt + (size_t)n0 * (D_ * 2);

  auto stage = [&](int buf, int k0) {
    int r0 = w * 16 + srow, r1 = w * 16 + 8 + srow;
    gload16(Ab + (size_t)r0 * (D_ * 2) + k0 * 2 + scb, &lA[buf][(w * 16) * 64]);
    gload16(Ab + (size_t)r1 * (D_ * 2) + k0 * 2 + scb, &lA[buf][(w * 16 + 8) * 64]);
    gload16(Bb + (size_t)r0 * (D_ * 2) + k0 * 2 + scb, &lB[buf][(w * 16) * 64]);
    gload16(Bb + (size_t)r1 * (D_ * 2) + k0 * 2 + scb, &lB[buf][(w * 16 + 8) * 64]);
  };

  f32x4 acc[4] = {};
  stage(0, 0);
  __syncthreads();
  int buf = 0;
  for (int t = 0; t < D_ / 64; ++t) {
    if (t + 1 < D_ / 64) stage(buf ^ 1, (t + 1) * 64);
    const char* pa = (const char*)&lA[buf][0];
    const char* pb = (const char*)&lB[buf][0];
#pragma unroll
    for (int kk = 0; kk < 2; ++kk) {
      int cs = (kk * 64 + g * 16) ^ sw;
      bf16x8 af = *(const bf16x8*)(pa + (w * 16 + c) * 128 + cs);
#pragma unroll
      for (int j = 0; j < 4; ++j) {
        bf16x8 bfj = *(const bf16x8*)(pb + (j * 16 + c) * 128 + cs);
        acc[j] = MFMA16(af, bfj, acc[j]);
      }
    }
    __syncthreads();
    buf ^= 1;
  }

#pragma unroll
  for (int j = 0; j < 4; ++j) {
    int n = n0 + j * 16 + c;
    float bv = bias[n];
    int h = n >> 6, d = n & 63;
    if (MODE == 1) {
      // m quad -> permuted V^T columns. sigma: slots 8q+0..3 <- keys 4q..;
      // slots 8q+4..7 <- keys 16+4q.. (within each 32-key chunk).
      int m = m0 + w * 16 + g * 4;
      int b = m >> 11, s = m & (S_ - 1);
      int chunk = s >> 5, kq = (s >> 2) & 7;
      int sb = kq < 4 ? 8 * kq : 8 * (kq - 4) + 4;
      float v0 = acc[j][0] + bv, v1 = acc[j][1] + bv;
      float v2 = acc[j][2] + bv, v3 = acc[j][3] + bv;
      uint2 pk;
      pk.x = pack2r(v0, v1);
      pk.y = pack2r(v2, v3);
      u16* dst = (u16*)outp + ((size_t)((b * H_ + h) * DH + d)) * S_ + chunk * 32 + sb;
      *(uint2*)dst = pk;
    } else {
#pragma unroll
      for (int r = 0; r < 4; ++r) {
        int m = m0 + w * 16 + g * 4 + r;
        float v = (acc[j][r] + bv) * scale;
        if (MODE == 0) {
          int b = m >> 11, s = m & (S_ - 1);
          ((u16*)outp)[((size_t)(b * H_ + h) * S_ + s) * DH + d] = f2bf(v);
        } else {
          ((float*)outp)[(size_t)m * D_ + n] = v;
        }
      }
    }
  }
}

// ---------------- dual-softmax flash attention (staged, 4 waves) -----------
// grid (S/64, B*H), block 256. Q pre-scaled by log2(e)/8 -> exp2 scores.
// V columns pre-permuted (sigma) so QK^T output regs ARE the PV A-fragment.
// fg/bg split via bitwise AND/XOR on packed bf16; row sums via ones-col MFMA.
__global__ __launch_bounds__(256, 3) void attn(const u16* __restrict__ Q,
                                               const u16* __restrict__ K,
                                               const u16* __restrict__ Vt,
                                               const float* __restrict__ fm,
                                               const u32* __restrict__ mw,
                                               u16* __restrict__ ctx) {
  constexpr int NT = S_ / 64;
  __shared__ __align__(16) u16 lK[2][64 * 64];
  __shared__ __align__(16) u16 lV[2][64 * 64];

  const int tid = threadIdx.x;
  const int w = tid >> 6, lane = tid & 63;
  const int g = lane >> 4, c = lane & 15;
  const int qt = blockIdx.x, bh = blockIdx.y;
  const int b = bh / H_, h = bh % H_;
  const int qbase = qt * 64;

  const u16* Qp = Q + ((size_t)bh * S_ + qbase + w * 16) * DH;
  const char* Kp = (const char*)(K + (size_t)bh * S_ * DH);
  const char* Vp = (const char*)(Vt + (size_t)bh * DH * S_);
  const float* fmp = fm + b * S_;
  const u32* mwp = mw + b * (S_ / 2);

  // Q fragments (B-operand): q = c, d-slices kk*32 + g*8
  bf16x8 qf0 = *(const bf16x8*)(Qp + c * DH + g * 8);
  bf16x8 qf1 = *(const bf16x8*)(Qp + c * DH + 32 + g * 8);

  // ones B-frag: col 0 = 1.0 for all k slots -> MFMA row-sum
  u32 ow = (c == 0) ? 0x3F803F80u : 0u;
  uint4 owv = {ow, ow, ow, ow};
  bf16x8 onesf = __builtin_bit_cast(bf16x8, owv);

  const int srow = lane >> 3;
  const int scb = ((lane & 7) * 16) ^ (srow << 4);
  const int r8a = w * 2, r8b = w * 2 + 1;
  const int rowA = r8a * 8 + srow, rowB = r8b * 8 + srow;
  const int sw = (c & 7) << 4;

  f32x4 accf[4] = {}, accb[4] = {}, alf = {}, alb = {};

  // prologue: stage tile 0 into buf 0
  gload16(Kp + (size_t)rowA * 128 + scb, &lK[0][r8a * 512]);
  gload16(Kp + (size_t)rowB * 128 + scb, &lK[0][r8b * 512]);
  gload16(Vp + (size_t)rowA * 4096 + scb, &lV[0][r8a * 512]);
  gload16(Vp + (size_t)rowB * 4096 + scb, &lV[0][r8b * 512]);
  __syncthreads();

  int buf = 0;
  for (int t = 0; t < NT; ++t) {
    if (t + 1 < NT) {
      const char* kb_ = Kp + (size_t)(t + 1) * 8192;
      const char* vb_ = Vp + (size_t)(t + 1) * 128;
      gload16(kb_ + (size_t)rowA * 128 + scb, &lK[buf ^ 1][r8a * 512]);
      gload16(kb_ + (size_t)rowB * 128 + scb, &lK[buf ^ 1][r8b * 512]);
      gload16(vb_ + (size_t)rowA * 4096 + scb, &lV[buf ^ 1][r8a * 512]);
      gload16(vb_ + (size_t)rowB * 4096 + scb, &lV[buf ^ 1][r8b * 512]);
    }
    const char* kt = (const char*)&lK[buf][0];
    const char* vtl = (const char*)&lV[buf][0];

#pragma unroll
    for (int kc = 0; kc < 2; ++kc) {
      const int csel = (kc * 64 + g * 16) ^ sw;
      // K fragments (A-operand): rows = keys (natural order)
      bf16x8 k00 = *(const bf16x8*)(kt + (kc * 32 + c) * 128 + ((g * 16) ^ sw));
      bf16x8 k01 = *(const bf16x8*)(kt + (kc * 32 + c) * 128 + ((64 + g * 16) ^ sw));
      bf16x8 k10 = *(const bf16x8*)(kt + (kc * 32 + 16 + c) * 128 + ((g * 16) ^ sw));
      bf16x8 k11 = *(const bf16x8*)(kt + (kc * 32 + 16 + c) * 128 + ((64 + g * 16) ^ sw));

      f32x4 st0 = {}, st1 = {};
      st0 = MFMA16(k00, qf0, st0);
      st0 = MFMA16(k01, qf1, st0);
      st1 = MFMA16(k10, qf0, st1);
      st1 = MFMA16(k11, qf1, st1);

      // lane (c,g) holds S[key][q=c]: st0 -> keys 4g+r, st1 -> keys 16+4g+r
      // (= PV A-frag slots 8g+0..3 and 8g+4..7 under the sigma V-permutation)
      u32 ew0 = pack2r(__builtin_amdgcn_exp2f(st0[0]), __builtin_amdgcn_exp2f(st0[1]));
      u32 ew1 = pack2r(__builtin_amdgcn_exp2f(st0[2]), __builtin_amdgcn_exp2f(st0[3]));
      u32 ew2 = pack2r(__builtin_amdgcn_exp2f(st1[0]), __builtin_amdgcn_exp2f(st1[1]));
      u32 ew3 = pack2r(__builtin_amdgcn_exp2f(st1[2]), __builtin_amdgcn_exp2f(st1[3]));

      const int pbase = ((t * 64 + kc * 32) >> 1);
      uint2 m01 = *(const uint2*)(mwp + pbase + 2 * g);      // keys 4g..4g+3
      uint2 m23 = *(const uint2*)(mwp + pbase + 8 + 2 * g);  // keys 16+4g..+3

      u32 pf0 = ew0 & m01.x, pf1 = ew1 & m01.y;
      u32 pf2 = ew2 & m23.x, pf3 = ew3 & m23.y;
      uint4 pfv = {pf0, pf1, pf2, pf3};
      uint4 pbv = {ew0 ^ pf0, ew1 ^ pf1, ew2 ^ pf2, ew3 ^ pf3};
      bf16x8 paf = __builtin_bit_cast(bf16x8, pfv);
      bf16x8 pab = __builtin_bit_cast(bf16x8, pbv);

      // V^T fragments (B-operand): rows = d, cols = sigma-slots of this 32-key slice
      bf16x8 vf0 = *(const bf16x8*)(vtl + (0 * 16 + c) * 128 + csel);
      bf16x8 vf1 = *(const bf16x8*)(vtl + (1 * 16 + c) * 128 + csel);
      bf16x8 vf2 = *(const bf16x8*)(vtl + (2 * 16 + c) * 128 + csel);
      bf16x8 vf3 = *(const bf16x8*)(vtl + (3 * 16 + c) * 128 + csel);

      accf[0] = MFMA16(paf, vf0, accf[0]);
      accb[0] = MFMA16(pab, vf0, accb[0]);
      accf[1] = MFMA16(paf, vf1, accf[1]);
      accb[1] = MFMA16(pab, vf1, accb[1]);
      accf[2] = MFMA16(paf, vf2, accf[2]);
      accb[2] = MFMA16(pab, vf2, accb[2]);
      accf[3] = MFMA16(paf, vf3, accf[3]);
      accb[3] = MFMA16(pab, vf3, accb[3]);
      alf = MFMA16(paf, onesf, alf);   // col0 = running lf per q
      alb = MFMA16(pab, onesf, alb);   // col0 = running lb per q
    }
    __syncthreads();
    buf ^= 1;
  }

  const int qw = qbase + w * 16;
#pragma unroll
  for (int r = 0; r < 4; ++r) {
    int ql = g * 4 + r;
    float lfr = __shfl(alf[r], g * 16);  // D[row=4g+r][col=0] lives in lane 16g
    float lbr = __shfl(alb[r], g * 16);
    bool fg = fmp[qw + ql] > 0.5f;
    float inv_f = (lfr > 0.f) ? 1.f / lfr : 0.f;
    float inv_b = (lbr > 0.f) ? 1.f / lbr : 0.f;
    float inv_all = 1.f / (lfr + lbr);
#pragma unroll
    for (int n = 0; n < 4; ++n) {
      float o = fg ? (accf[n][r] * inv_f + accb[n][r] * inv_b)
                   : ((accf[n][r] + accb[n][r]) * inv_all);
      ctx[((size_t)(b * S_ + qw + ql)) * D_ + h * DH + n * 16 + c] = f2bf(o);
    }
  }
}

// ---------------- launch ---------------------------------------------------
extern "C" void kernel_launch(void* const* d_in, const int* in_sizes, int n_in,
                              void* d_out, int out_size, void* d_ws, size_t ws_size,
                              hipStream_t stream) {
  const float* hs = (const float*)d_in[0];
  const float* Wq = (const float*)d_in[1];
  const float* bq = (const float*)d_in[2];
  const float* Wk = (const float*)d_in[3];
  const float* bk = (const float*)d_in[4];
  const float* Wv = (const float*)d_in[5];
  const float* bv = (const float*)d_in[6];
  const float* Wo = (const float*)d_in[7];
  const float* bo = (const float*)d_in[8];
  const void* mraw = d_in[9];

  char* ws = (char*)d_ws;
  size_t off = 0;
  auto alloc = [&](size_t bytes) {
    void* p = ws + off;
    off += (bytes + 255) & ~(size_t)255;
    return p;
  };
  u16* hsb = (u16*)alloc((size_t)M_ * D_ * 2);
  u16* wqT = (u16*)alloc((size_t)D_ * D_ * 2);
  u16* wkT = (u16*)alloc((size_t)D_ * D_ * 2);
  u16* wvT = (u16*)alloc((size_t)D_ * D_ * 2);
  u16* woT = (u16*)alloc((size_t)D_ * D_ * 2);
  u16* qb = (u16*)alloc((size_t)M_ * D_ * 2);
  u16* kb = (u16*)alloc((size_t)M_ * D_ * 2);
  u16* vtb = (u16*)alloc((size_t)M_ * D_ * 2);
  u16* ctx = (u16*)alloc((size_t)M_ * D_ * 2);
  float* fmf = (float*)alloc((size_t)B_ * S_ * 4);
  u32* mwb = (u32*)alloc((size_t)B_ * S_ / 2 * 4);

  conv_bf16<<<(M_ * D_ / 4 + 255) / 256, 256, 0, stream>>>(hs, hsb);
  WPtrs wp = {Wq, Wk, Wv, Wo, wqT, wkT, wvT, woT};
  conv_wT4<<<dim3(D_ / 32, D_ / 32, 4), 256, 0, stream>>>(wp);
  canon_mask<<<B_ * S_ / 512, 256, 0, stream>>>(mraw, fmf, mwb);

  dim3 gg(M_ / 64, D_ / 64);
  const float qscale = 0.125f * 1.44269504088896f;  // 1/sqrt(Dh) * log2(e)
  gemm64<0><<<gg, 256, 0, stream>>>(hsb, wqT, bq, qb, qscale);
  gemm64<0><<<gg, 256, 0, stream>>>(hsb, wkT, bk, kb, 1.0f);
  gemm64<1><<<gg, 256, 0, stream>>>(hsb, wvT, bv, vtb, 1.0f);

  attn<<<dim3(S_ / 64, BH), 256, 0, stream>>>(qb, kb, vtb, fmf, mwb, ctx);

  gemm64<2><<<gg, 256, 0, stream>>>(ctx, woT, bo, d_out, 1.0f);
}